// Round 6
// baseline (216.237 us; speedup 1.0000x reference)
//
#include <hip/hip_runtime.h>
#include <cstdint>
#include <cstddef>

#define B_ 8
#define T_ 2048
#define F_ 512
#define D_ 256
#define NSPLIT 2               // KV split; keys per split-block = 1024
#define KVB 64                 // keys per LDS tile
#define NT ((T_ / NSPLIT) / KVB)   // 16 iterations

typedef float f32x4 __attribute__((ext_vector_type(4)));
typedef __bf16 bf16x8 __attribute__((ext_vector_type(8)));
typedef unsigned short us8 __attribute__((ext_vector_type(8)));
typedef unsigned short us4 __attribute__((ext_vector_type(4)));

static __device__ __forceinline__ unsigned short f2bf(float f) {
  union { float f; unsigned int u; } v; v.f = f;
  unsigned int u = v.u;
  u += 0x7fffu + ((u >> 16) & 1u);   // RNE
  return (unsigned short)(u >> 16);
}

static __device__ __forceinline__ float bf2f(unsigned short s) {
  union { float f; unsigned int u; } v; v.u = ((unsigned int)s) << 16;
  return v.f;
}

static __device__ __forceinline__ bf16x8 ldb8(const unsigned short* p) {
  return *reinterpret_cast<const bf16x8*>(p);
}

static __device__ __forceinline__ bf16x8 asbf(f32x4 v) {
  union { f32x4 f; bf16x8 b; } u; u.f = v; return u.b;
}

static __device__ __forceinline__ f32x4 mfma_bf16(bf16x8 a, bf16x8 b, f32x4 c) {
  return __builtin_amdgcn_mfma_f32_16x16x32_bf16(a, b, c, 0, 0, 0);
}

// async global -> LDS, 16 B per lane (dest must be linear: base + lane*16)
static __device__ __forceinline__ void gload_lds16(const unsigned short* g,
                                                   unsigned short* l) {
  __builtin_amdgcn_global_load_lds(
      (const __attribute__((address_space(1))) void*)g,
      (__attribute__((address_space(3))) void*)l, 16, 0, 0);
}

// ---------------------------------------------------------------------------
// Kernel 0: convert X f32 -> bf16 (8.4M elems, BW-bound)
// ---------------------------------------------------------------------------
__global__ __launch_bounds__(256) void xb_kernel(const float* __restrict__ X,
                                                 unsigned short* __restrict__ Xb) {
  size_t i = ((size_t)blockIdx.x * 256 + threadIdx.x) * 8;
  float4 a = *reinterpret_cast<const float4*>(&X[i]);
  float4 b = *reinterpret_cast<const float4*>(&X[i + 4]);
  us8 p;
  p[0] = f2bf(a.x); p[1] = f2bf(a.y); p[2] = f2bf(a.z); p[3] = f2bf(a.w);
  p[4] = f2bf(b.x); p[5] = f2bf(b.y); p[6] = f2bf(b.z); p[7] = f2bf(b.w);
  *reinterpret_cast<us8*>(&Xb[i]) = p;
}

// ---------------------------------------------------------------------------
// Kernel 1: transpose + convert the three W matrices: [F,D] f32 -> [D,F] bf16
// ---------------------------------------------------------------------------
__global__ __launch_bounds__(256) void tw_kernel(const float* __restrict__ Wq,
                                                 const float* __restrict__ Wk,
                                                 const float* __restrict__ Wv,
                                                 unsigned short* __restrict__ Wt) {
  __shared__ unsigned short tile[64][72];
  const float* W = (blockIdx.z == 0) ? Wq : (blockIdx.z == 1) ? Wk : Wv;
  unsigned short* out = Wt + (size_t)blockIdx.z * (D_ * F_);
  int k0 = blockIdx.x * 64, n0 = blockIdx.y * 64;
  int t = threadIdx.x;
#pragma unroll
  for (int i = 0; i < 4; i++) {
    int c = t + 256 * i;
    int r = c >> 4, c4 = (c & 15) * 4;
    float4 v = *reinterpret_cast<const float4*>(&W[(size_t)(k0 + r) * D_ + n0 + c4]);
    us4 p; p[0] = f2bf(v.x); p[1] = f2bf(v.y); p[2] = f2bf(v.z); p[3] = f2bf(v.w);
    *reinterpret_cast<us4*>(&tile[r][c4]) = p;
  }
  __syncthreads();
#pragma unroll
  for (int i = 0; i < 4; i++) {
    int c = t + 256 * i;
    int r = c >> 4, c4 = (c & 15) * 4;
    us4 p;
    p[0] = tile[c4 + 0][r];
    p[1] = tile[c4 + 1][r];
    p[2] = tile[c4 + 2][r];
    p[3] = tile[c4 + 3][r];
    *reinterpret_cast<us4*>(&out[(size_t)(n0 + r) * F_ + k0 + c4]) = p;
  }
}

// ---------------------------------------------------------------------------
// Kernel 2: projection GEMM, m97-style: bf16 A/B both staged via
// global_load_lds (linear LDS + both-sides XOR swizzle), double-buffered.
// grid (128, 2, 3), block 256 (4 waves). LDS 64KB -> 2 blocks/CU.
// ---------------------------------------------------------------------------
__global__ __launch_bounds__(256) void proj_kernel(const unsigned short* __restrict__ Xb,
                                                   const unsigned short* __restrict__ Wt,
                                                   unsigned short* __restrict__ Qs,
                                                   unsigned short* __restrict__ Kb,
                                                   unsigned short* __restrict__ Vt) {
  __shared__ unsigned short Au[2][128 * 64];   // [row][64 bf16], swizzled content
  __shared__ unsigned short Bu[2][128 * 64];
  const int brow = blockIdx.x * 128;
  const int bcol = blockIdx.y * 128;
  const int z = blockIdx.z;
  const unsigned short* W = Wt + (size_t)z * (D_ * F_);
  const int tid = threadIdx.x;
  const int wave = tid >> 6, lane = tid & 63;
  const int wr = wave >> 1, wc = wave & 1;
  const int lg = lane >> 4, lr = lane & 15;

  f32x4 acc[4][4] = {};

  // stage one 128x64 bf16 tile (16KB): 4 gload16/thread, source pre-swizzled
  auto stageT = [&](unsigned short* dst, const unsigned short* srcBase, int k0) {
#pragma unroll
    for (int i = 0; i < 4; i++) {
      int L = (tid + 256 * i) * 16;     // LDS byte 0..16383
      int r = L >> 7;                   // tile row (128 B/row)
      int c = L & 127;
      int csw = c ^ ((r & 7) << 4);
      gload_lds16(srcBase + (size_t)r * F_ + k0 + (csw >> 1), dst + (L >> 1));
    }
  };

  stageT(Au[0], Xb + (size_t)brow * F_, 0);
  stageT(Bu[0], W + (size_t)bcol * F_, 0);
  __syncthreads();

  for (int ks = 0; ks < 8; ks++) {
    const int cur = ks & 1;
    if (ks + 1 < 8) {
      stageT(Au[cur ^ 1], Xb + (size_t)brow * F_, (ks + 1) * 64);
      stageT(Bu[cur ^ 1], W + (size_t)bcol * F_, (ks + 1) * 64);
    }
#pragma unroll
    for (int kk = 0; kk < 2; kk++) {
      bf16x8 af[4], bfr[4];
#pragma unroll
      for (int mi = 0; mi < 4; mi++) {
        int r = wr * 64 + mi * 16 + lr;
        af[mi] = ldb8(&Au[cur][r * 64 + ((((kk * 64 + lg * 16) ^ ((r & 7) << 4))) >> 1)]);
      }
#pragma unroll
      for (int ni = 0; ni < 4; ni++) {
        int r = wc * 64 + ni * 16 + lr;
        bfr[ni] = ldb8(&Bu[cur][r * 64 + ((((kk * 64 + lg * 16) ^ ((r & 7) << 4))) >> 1)]);
      }
#pragma unroll
      for (int mi = 0; mi < 4; mi++)
#pragma unroll
        for (int ni = 0; ni < 4; ni++)
          acc[mi][ni] = mfma_bf16(af[mi], bfr[ni], acc[mi][ni]);
    }
    __syncthreads();
  }

#pragma unroll
  for (int mi = 0; mi < 4; mi++) {
#pragma unroll
    for (int ni = 0; ni < 4; ni++) {
      int row0 = brow + wr * 64 + mi * 16 + lg * 4;
      int col = bcol + wc * 64 + ni * 16 + lr;
      if (z == 0) {
#pragma unroll
        for (int j = 0; j < 4; j++)
          Qs[(size_t)(row0 + j) * D_ + col] = f2bf(acc[mi][ni][j] * 0.0625f);
      } else if (z == 1) {
#pragma unroll
        for (int j = 0; j < 4; j++)
          Kb[(size_t)(row0 + j) * D_ + col] = f2bf(acc[mi][ni][j]);
      } else {
        int b = row0 >> 11, t0 = row0 & (T_ - 1);
        us4 p;
#pragma unroll
        for (int j = 0; j < 4; j++) p[j] = f2bf(acc[mi][ni][j]);
        *reinterpret_cast<us4*>(&Vt[(size_t)b * D_ * T_ + (size_t)col * T_ + t0]) = p;
      }
    }
  }
}

// ---------------------------------------------------------------------------
// Kernel 3: flash attention. grid (B, T/64, NSPLIT), block 256 (4 waves).
// waves_per_eu(2,2): allocator free to use 256 VGPR (LDS caps at 2 blk/CU
// anyway) -> V fragments held in registers across softmax.
// ---------------------------------------------------------------------------
__global__ __launch_bounds__(256)
__attribute__((amdgpu_waves_per_eu(2, 2)))
void flash_kernel(const unsigned short* __restrict__ Qs,
                  const unsigned short* __restrict__ Kb,
                  const unsigned short* __restrict__ Vt,
                  unsigned short* __restrict__ op,
                  float2* __restrict__ ml) {
  __shared__ unsigned short Kl[2][KVB * 256];   // 2 x 32KB, row-swizzled content
  __shared__ unsigned short Pl[4][16][68];      // P in PV-A layout: [q][key]

  const int b = blockIdx.x, qt = blockIdx.y, h = blockIdx.z;  // XCD = linear%8 = b
  const int tid = threadIdx.x;
  const int wave = tid >> 6, lane = tid & 63;
  const int lg = lane >> 4, lr = lane & 15;
  const int swz = (lr & 7) << 4;   // byte XOR for this lane's K rows

  const int qrow = qt * 64 + wave * 16 + lr;
  const unsigned short* qptr = Qs + ((size_t)b * T_ + qrow) * D_;
  bf16x8 qf[8];
#pragma unroll
  for (int ks = 0; ks < 8; ks++) qf[ks] = ldb8(qptr + ks * 32 + lg * 8);

  f32x4 o[16] = {};
  float m = -__builtin_inff();   // running max for q = lr (replicated over lg)
  float lsum = 0.f;              // running denom for q = lr

  const int keyoff = h * (T_ / NSPLIT);
  const unsigned short* kbase = Kb + (size_t)b * T_ * D_ + (size_t)keyoff * D_;
  const unsigned short* vbase = Vt + (size_t)b * D_ * T_;

  auto stage = [&](int buf, int kt) {
    const unsigned short* src = kbase + (size_t)kt * KVB * D_;
#pragma unroll
    for (int i = 0; i < 8; i++) {
      int L = (tid + 256 * i) * 16;        // LDS byte offset, 0..32767
      int r = L >> 9;                      // tile-local key row
      int c = L & 511;                     // byte col
      int csw = c ^ ((r & 7) << 4);
      gload_lds16(src + r * 256 + (csw >> 1), &Kl[buf][L >> 1]);
    }
  };

  stage(0, 0);
  __syncthreads();

  for (int kt = 0; kt < NT; kt++) {
    const int cur = kt & 1;
    if (kt + 1 < NT) stage(cur ^ 1, kt + 1);   // async prefetch next tile
    const int key0 = keyoff + kt * KVB;

    // ---- V half-1 prefetch BEFORE QK: L2 latency hides under QK+softmax ----
    f32x4 v0[16];
#pragma unroll
    for (int nf = 0; nf < 16; nf++)
      v0[nf] = *reinterpret_cast<const f32x4*>(
          &vbase[(size_t)(nf * 16 + lr) * T_ + key0 + lg * 8]);

    // ---- S^T = K * Q^T : lane holds 16 scores, all for q = lr ----
    f32x4 s[4] = {};
    __builtin_amdgcn_s_setprio(1);
#pragma unroll
    for (int ks = 0; ks < 8; ks++) {
#pragma unroll
      for (int nf = 0; nf < 4; nf++) {
        bf16x8 kb = ldb8(&Kl[cur][(nf * 16 + lr) * 256 + (((ks * 64 + lg * 16) ^ swz) >> 1)]);
        s[nf] = mfma_bf16(kb, qf[ks], s[nf]);
      }
    }
    __builtin_amdgcn_s_setprio(0);

    // ---- V half-2 loads issued here; scheduler hoists with free VGPRs ----
    f32x4 v1[16];
#pragma unroll
    for (int nf = 0; nf < 16; nf++)
      v1[nf] = *reinterpret_cast<const f32x4*>(
          &vbase[(size_t)(nf * 16 + lr) * T_ + key0 + 32 + lg * 8]);

    // ---- lane-local softmax for q = lr ----
    float pm;
    {
      float a0 = fmaxf(fmaxf(s[0][0], s[0][1]), fmaxf(s[0][2], s[0][3]));
      float a1 = fmaxf(fmaxf(s[1][0], s[1][1]), fmaxf(s[1][2], s[1][3]));
      float a2 = fmaxf(fmaxf(s[2][0], s[2][1]), fmaxf(s[2][2], s[2][3]));
      float a3 = fmaxf(fmaxf(s[3][0], s[3][1]), fmaxf(s[3][2], s[3][3]));
      pm = fmaxf(fmaxf(a0, a1), fmaxf(a2, a3));
      pm = fmaxf(pm, __shfl_xor(pm, 16));
      pm = fmaxf(pm, __shfl_xor(pm, 32));
    }
    if (!__all(pm - m <= 8.0f)) {            // defer-max (T13, THR=8)
      float mn = fmaxf(m, pm);
      float corr = __expf(m - mn);
      m = mn;
      lsum *= corr;
      float c4[4];
#pragma unroll
      for (int j = 0; j < 4; j++) c4[j] = __shfl(corr, lg * 4 + j);  // corr for q=4lg+j
#pragma unroll
      for (int nf = 0; nf < 16; nf++)
#pragma unroll
        for (int j = 0; j < 4; j++) o[nf][j] *= c4[j];
    }
    float rs = 0.f;
#pragma unroll
    for (int nf = 0; nf < 4; nf++) {
      us4 pk;
#pragma unroll
      for (int j = 0; j < 4; j++) {
        float p = __expf(s[nf][j] - m);
        rs += p;
        pk[j] = f2bf(p);
      }
      *reinterpret_cast<us4*>(&Pl[wave][lr][nf * 16 + lg * 4]) = pk;
    }
    rs += __shfl_xor(rs, 16);
    rs += __shfl_xor(rs, 32);
    lsum += rs;

    // ---- O += P * V : both halves from registers ----
    __builtin_amdgcn_s_setprio(1);
    {
      bf16x8 pa = ldb8(&Pl[wave][lr][lg * 8]);
#pragma unroll
      for (int nf = 0; nf < 16; nf++) o[nf] = mfma_bf16(pa, asbf(v0[nf]), o[nf]);
    }
    {
      bf16x8 pa = ldb8(&Pl[wave][lr][32 + lg * 8]);
#pragma unroll
      for (int nf = 0; nf < 16; nf++) o[nf] = mfma_bf16(pa, asbf(v1[nf]), o[nf]);
    }
    __builtin_amdgcn_s_setprio(0);

    __syncthreads();   // drains stage loads; next iter flips buffers
  }

  // ---- write partials (unnormalized o in bf16; m/l in f32 at q = lr) ----
  const size_t rowbase = (size_t)h * (B_ * T_) + (size_t)b * T_;
#pragma unroll
  for (int nf = 0; nf < 16; nf++) {
#pragma unroll
    for (int j = 0; j < 4; j++) {
      int q = qt * 64 + wave * 16 + lg * 4 + j;
      op[(rowbase + q) * D_ + nf * 16 + lr] = f2bf(o[nf][j]);
    }
  }
  if (lg == 0) {
    int q = qt * 64 + wave * 16 + lr;
    ml[rowbase + q] = make_float2(m, lsum);
  }
}

// ---------------------------------------------------------------------------
// Kernel 4: merge NSPLIT partials.  grid (B*T/4), block 256: 4 rows/block.
// ---------------------------------------------------------------------------
__global__ __launch_bounds__(256) void merge_kernel(const unsigned short* __restrict__ op,
                                                    const float2* __restrict__ ml,
                                                    float* __restrict__ out) {
  const int tid = threadIdx.x;
  const int row = blockIdx.x * 4 + (tid >> 6);
  const int d0 = (tid & 63) * 4;

  float mh[NSPLIT], lh[NSPLIT];
  float M = -__builtin_inff();
#pragma unroll
  for (int hh = 0; hh < NSPLIT; hh++) {
    float2 v = ml[(size_t)hh * (B_ * T_) + row];
    mh[hh] = v.x; lh[hh] = v.y;
    M = fmaxf(M, v.x);
  }
  float e[NSPLIT], den = 0.f;
#pragma unroll
  for (int hh = 0; hh < NSPLIT; hh++) {
    e[hh] = __expf(mh[hh] - M);
    den += e[hh] * lh[hh];
  }
  const float inv = 1.0f / den;

  float acc[4] = {0.f, 0.f, 0.f, 0.f};
#pragma unroll
  for (int hh = 0; hh < NSPLIT; hh++) {
    us4 p = *reinterpret_cast<const us4*>(
        &op[((size_t)hh * (B_ * T_) + row) * D_ + d0]);
#pragma unroll
    for (int j = 0; j < 4; j++) acc[j] += e[hh] * bf2f(p[j]);
  }
  float4 r;
  r.x = acc[0] * inv; r.y = acc[1] * inv; r.z = acc[2] * inv; r.w = acc[3] * inv;
  *reinterpret_cast<float4*>(&out[(size_t)row * D_ + d0]) = r;
}

// ---------------------------------------------------------------------------
extern "C" void kernel_launch(void* const* d_in, const int* in_sizes, int n_in,
                              void* d_out, int out_size, void* d_ws, size_t ws_size,
                              hipStream_t stream) {
  const float* X  = (const float*)d_in[0];
  const float* Wq = (const float*)d_in[1];
  const float* Wk = (const float*)d_in[2];
  const float* Wv = (const float*)d_in[3];
  float* out = (float*)d_out;

  char* ws = (char*)d_ws;
  // Wt 0.75MB | Qs 8MB | Kb 8MB | Vt 8MB | op 16MB (aliased w/ Xb) | ml 0.25MB
  unsigned short* Wt = (unsigned short*)ws;
  unsigned short* Qs = (unsigned short*)(ws + 786432);
  unsigned short* Kb = (unsigned short*)(ws + 786432 + 8388608);
  unsigned short* Vt = (unsigned short*)(ws + 786432 + 2 * 8388608);
  unsigned short* op = (unsigned short*)(ws + 786432 + 3 * 8388608);
  unsigned short* Xb = op;   // alias: Xb consumed by proj before flash writes op
  float2* ml        = (float2*)(ws + 786432 + 3 * 8388608 + (size_t)NSPLIT * B_ * T_ * D_ * 2);

  xb_kernel<<<dim3((B_ * T_ * F_) / (256 * 8)), 256, 0, stream>>>(X, Xb);
  tw_kernel<<<dim3(F_ / 64, D_ / 64, 3), 256, 0, stream>>>(Wq, Wk, Wv, Wt);
  proj_kernel<<<dim3((B_ * T_) / 128, D_ / 128, 3), 256, 0, stream>>>(Xb, Wt, Qs, Kb, Vt);
  flash_kernel<<<dim3(B_, T_ / 64, NSPLIT), 256, 0, stream>>>(Qs, Kb, Vt, op, ml);
  merge_kernel<<<dim3(B_ * T_ / 4), 256, 0, stream>>>(op, ml, out);
}

// Round 7
// 106.617 us; speedup vs baseline: 2.0282x; 2.0282x over previous
//
#include <hip/hip_runtime.h>
#include <cstdint>
#include <cstddef>

#define B_ 8
#define T_ 2048
#define F_ 512
#define D_ 256
#define NSPLIT 2               // KV split; keys per split-block = 1024
#define KVB 32                 // keys per LDS tile
#define NT ((T_ / NSPLIT) / KVB)   // 32 iterations

typedef float f32x4 __attribute__((ext_vector_type(4)));
typedef __bf16 bf16x8 __attribute__((ext_vector_type(8)));
typedef unsigned short us8 __attribute__((ext_vector_type(8)));
typedef unsigned short us4 __attribute__((ext_vector_type(4)));

static __device__ __forceinline__ unsigned short f2bf(float f) {
  union { float f; unsigned int u; } v; v.f = f;
  unsigned int u = v.u;
  u += 0x7fffu + ((u >> 16) & 1u);   // RNE
  return (unsigned short)(u >> 16);
}

static __device__ __forceinline__ float bf2f(unsigned short s) {
  union { float f; unsigned int u; } v; v.u = ((unsigned int)s) << 16;
  return v.f;
}

static __device__ __forceinline__ bf16x8 ldb8(const unsigned short* p) {
  return *reinterpret_cast<const bf16x8*>(p);
}

static __device__ __forceinline__ f32x4 mfma_bf16(bf16x8 a, bf16x8 b, f32x4 c) {
  return __builtin_amdgcn_mfma_f32_16x16x32_bf16(a, b, c, 0, 0, 0);
}

// async global -> LDS, 16 B per lane (dest must be linear: base + lane*16)
static __device__ __forceinline__ void gload_lds16(const unsigned short* g,
                                                   unsigned short* l) {
  __builtin_amdgcn_global_load_lds(
      (const __attribute__((address_space(1))) void*)g,
      (__attribute__((address_space(3))) void*)l, 16, 0, 0);
}

// ---------------------------------------------------------------------------
// Kernel 0: convert X f32 -> bf16 (8.4M elems, BW-bound)
// ---------------------------------------------------------------------------
__global__ __launch_bounds__(256) void xb_kernel(const float* __restrict__ X,
                                                 unsigned short* __restrict__ Xb) {
  size_t i = ((size_t)blockIdx.x * 256 + threadIdx.x) * 8;
  float4 a = *reinterpret_cast<const float4*>(&X[i]);
  float4 b = *reinterpret_cast<const float4*>(&X[i + 4]);
  us8 p;
  p[0] = f2bf(a.x); p[1] = f2bf(a.y); p[2] = f2bf(a.z); p[3] = f2bf(a.w);
  p[4] = f2bf(b.x); p[5] = f2bf(b.y); p[6] = f2bf(b.z); p[7] = f2bf(b.w);
  *reinterpret_cast<us8*>(&Xb[i]) = p;
}

// ---------------------------------------------------------------------------
// Kernel 1: transpose + convert the three W matrices: [F,D] f32 -> [D,F] bf16
// ---------------------------------------------------------------------------
__global__ __launch_bounds__(256) void tw_kernel(const float* __restrict__ Wq,
                                                 const float* __restrict__ Wk,
                                                 const float* __restrict__ Wv,
                                                 unsigned short* __restrict__ Wt) {
  __shared__ unsigned short tile[64][72];
  const float* W = (blockIdx.z == 0) ? Wq : (blockIdx.z == 1) ? Wk : Wv;
  unsigned short* out = Wt + (size_t)blockIdx.z * (D_ * F_);
  int k0 = blockIdx.x * 64, n0 = blockIdx.y * 64;
  int t = threadIdx.x;
#pragma unroll
  for (int i = 0; i < 4; i++) {
    int c = t + 256 * i;
    int r = c >> 4, c4 = (c & 15) * 4;
    float4 v = *reinterpret_cast<const float4*>(&W[(size_t)(k0 + r) * D_ + n0 + c4]);
    us4 p; p[0] = f2bf(v.x); p[1] = f2bf(v.y); p[2] = f2bf(v.z); p[3] = f2bf(v.w);
    *reinterpret_cast<us4*>(&tile[r][c4]) = p;
  }
  __syncthreads();
#pragma unroll
  for (int i = 0; i < 4; i++) {
    int c = t + 256 * i;
    int r = c >> 4, c4 = (c & 15) * 4;
    us4 p;
    p[0] = tile[c4 + 0][r];
    p[1] = tile[c4 + 1][r];
    p[2] = tile[c4 + 2][r];
    p[3] = tile[c4 + 3][r];
    *reinterpret_cast<us4*>(&out[(size_t)(n0 + r) * F_ + k0 + c4]) = p;
  }
}

// ---------------------------------------------------------------------------
// Kernel 2: projection GEMM, m97-style: bf16 A/B both staged via
// global_load_lds (linear LDS + both-sides XOR swizzle), double-buffered.
// ---------------------------------------------------------------------------
__global__ __launch_bounds__(256) void proj_kernel(const unsigned short* __restrict__ Xb,
                                                   const unsigned short* __restrict__ Wt,
                                                   unsigned short* __restrict__ Qs,
                                                   unsigned short* __restrict__ Kb,
                                                   unsigned short* __restrict__ Vt) {
  __shared__ unsigned short Au[2][128 * 64];   // [row][64 bf16], swizzled content
  __shared__ unsigned short Bu[2][128 * 64];
  const int brow = blockIdx.x * 128;
  const int bcol = blockIdx.y * 128;
  const int z = blockIdx.z;
  const unsigned short* W = Wt + (size_t)z * (D_ * F_);
  const int tid = threadIdx.x;
  const int wave = tid >> 6, lane = tid & 63;
  const int wr = wave >> 1, wc = wave & 1;
  const int lg = lane >> 4, lr = lane & 15;

  f32x4 acc[4][4] = {};

  auto stageT = [&](unsigned short* dst, const unsigned short* srcBase, int k0) {
#pragma unroll
    for (int i = 0; i < 4; i++) {
      int L = (tid + 256 * i) * 16;     // LDS byte 0..16383
      int r = L >> 7;                   // tile row (128 B/row)
      int c = L & 127;
      int csw = c ^ ((r & 7) << 4);
      gload_lds16(srcBase + (size_t)r * F_ + k0 + (csw >> 1), dst + (L >> 1));
    }
  };

  stageT(Au[0], Xb + (size_t)brow * F_, 0);
  stageT(Bu[0], W + (size_t)bcol * F_, 0);
  __syncthreads();

  for (int ks = 0; ks < 8; ks++) {
    const int cur = ks & 1;
    if (ks + 1 < 8) {
      stageT(Au[cur ^ 1], Xb + (size_t)brow * F_, (ks + 1) * 64);
      stageT(Bu[cur ^ 1], W + (size_t)bcol * F_, (ks + 1) * 64);
    }
#pragma unroll
    for (int kk = 0; kk < 2; kk++) {
      bf16x8 af[4], bfr[4];
#pragma unroll
      for (int mi = 0; mi < 4; mi++) {
        int r = wr * 64 + mi * 16 + lr;
        af[mi] = ldb8(&Au[cur][r * 64 + ((((kk * 64 + lg * 16) ^ ((r & 7) << 4))) >> 1)]);
      }
#pragma unroll
      for (int ni = 0; ni < 4; ni++) {
        int r = wc * 64 + ni * 16 + lr;
        bfr[ni] = ldb8(&Bu[cur][r * 64 + ((((kk * 64 + lg * 16) ^ ((r & 7) << 4))) >> 1)]);
      }
#pragma unroll
      for (int mi = 0; mi < 4; mi++)
#pragma unroll
        for (int ni = 0; ni < 4; ni++)
          acc[mi][ni] = mfma_bf16(af[mi], bfr[ni], acc[mi][ni]);
    }
    __syncthreads();
  }

#pragma unroll
  for (int mi = 0; mi < 4; mi++) {
#pragma unroll
    for (int ni = 0; ni < 4; ni++) {
      int row0 = brow + wr * 64 + mi * 16 + lg * 4;
      int col = bcol + wc * 64 + ni * 16 + lr;
      if (z == 0) {
#pragma unroll
        for (int j = 0; j < 4; j++)
          Qs[(size_t)(row0 + j) * D_ + col] = f2bf(acc[mi][ni][j] * 0.0625f);
      } else if (z == 1) {
#pragma unroll
        for (int j = 0; j < 4; j++)
          Kb[(size_t)(row0 + j) * D_ + col] = f2bf(acc[mi][ni][j]);
      } else {
        int b = row0 >> 11, t0 = row0 & (T_ - 1);
        us4 p;
#pragma unroll
        for (int j = 0; j < 4; j++) p[j] = f2bf(acc[mi][ni][j]);
        *reinterpret_cast<us4*>(&Vt[(size_t)b * D_ * T_ + (size_t)col * T_ + t0]) = p;
      }
    }
  }
}

// ---------------------------------------------------------------------------
// Kernel 3: flash attention. grid (B, T/64, NSPLIT), block 256 (4 waves).
// KVB=32: K AND V both double-buffered in LDS via global_load_lds (async,
// no VGPR cost), both-sides XOR swizzle. PV reads V from LDS (~12cy batched)
// instead of serialized 200cy L2 loads.
// ---------------------------------------------------------------------------
__global__ __launch_bounds__(256)
void flash_kernel(const unsigned short* __restrict__ Qs,
                  const unsigned short* __restrict__ Kb,
                  const unsigned short* __restrict__ Vt,
                  unsigned short* __restrict__ op,
                  float2* __restrict__ ml) {
  __shared__ unsigned short Kl[2][KVB * 256];   // 2 x 16KB, [key][d] swizzled
  __shared__ unsigned short Vl[2][256 * KVB];   // 2 x 16KB, [d][key] swizzled
  __shared__ unsigned short Pl[4][16][40];      // P: [q][key(32)] per wave

  const int b = blockIdx.x, qt = blockIdx.y, h = blockIdx.z;  // XCD = linear%8 = b
  const int tid = threadIdx.x;
  const int wave = tid >> 6, lane = tid & 63;
  const int lg = lane >> 4, lr = lane & 15;

  const int qrow = qt * 64 + wave * 16 + lr;
  const unsigned short* qptr = Qs + ((size_t)b * T_ + qrow) * D_;
  bf16x8 qf[8];
#pragma unroll
  for (int ks = 0; ks < 8; ks++) qf[ks] = ldb8(qptr + ks * 32 + lg * 8);

  f32x4 o[16] = {};
  float m = -__builtin_inff();   // running max for q = lr (replicated over lg)
  float lsum = 0.f;              // running denom for q = lr

  const int keyoff = h * (T_ / NSPLIT);
  const unsigned short* kbase = Kb + (size_t)b * T_ * D_ + (size_t)keyoff * D_;
  const unsigned short* vbase = Vt + (size_t)b * D_ * T_;

  // stage K tile [32][256] and V^T tile [256][32] for key block kt
  auto stage = [&](int buf, int kt) {
    const unsigned short* ksrc = kbase + (size_t)kt * KVB * D_;
#pragma unroll
    for (int i = 0; i < 4; i++) {
      int L = (tid + 256 * i) * 16;        // 0..16383
      int r = L >> 9;                      // key row (512 B/row)
      int c = L & 511;
      int csw = c ^ ((r & 7) << 4);
      gload_lds16(ksrc + r * 256 + (csw >> 1), &Kl[buf][L >> 1]);
    }
    const int key0 = keyoff + kt * KVB;
#pragma unroll
    for (int i = 0; i < 4; i++) {
      int L = (tid + 256 * i) * 16;        // 0..16383
      int d = L >> 6;                      // d row (64 B/row)
      int c = L & 63;
      int csw = c ^ (((d >> 1) & 3) << 4);
      gload_lds16(vbase + (size_t)d * T_ + key0 + (csw >> 1), &Vl[buf][L >> 1]);
    }
  };

  stage(0, 0);
  __syncthreads();

  for (int kt = 0; kt < NT; kt++) {
    const int cur = kt & 1;
    if (kt + 1 < NT) stage(cur ^ 1, kt + 1);   // async prefetch next tiles

    // ---- S^T = K * Q^T : lane holds 8 scores, all for q = lr ----
    // s[nf][j] = score(q=lr, key = nf*16 + 4*lg + j)
    f32x4 s[2] = {};
    __builtin_amdgcn_s_setprio(1);
#pragma unroll
    for (int ks = 0; ks < 8; ks++) {
#pragma unroll
      for (int nf = 0; nf < 2; nf++) {
        int r = nf * 16 + lr;
        bf16x8 kb = ldb8(&Kl[cur][r * 256 + (((ks * 64 + lg * 16) ^ ((r & 7) << 4)) >> 1)]);
        s[nf] = mfma_bf16(kb, qf[ks], s[nf]);
      }
    }
    __builtin_amdgcn_s_setprio(0);

    // ---- lane-local softmax for q = lr (8 scores) ----
    float pm;
    {
      float a0 = fmaxf(fmaxf(s[0][0], s[0][1]), fmaxf(s[0][2], s[0][3]));
      float a1 = fmaxf(fmaxf(s[1][0], s[1][1]), fmaxf(s[1][2], s[1][3]));
      pm = fmaxf(a0, a1);
      pm = fmaxf(pm, __shfl_xor(pm, 16));
      pm = fmaxf(pm, __shfl_xor(pm, 32));
    }
    if (!__all(pm - m <= 8.0f)) {            // defer-max (T13, THR=8)
      float mn = fmaxf(m, pm);
      float corr = __expf(m - mn);
      m = mn;
      lsum *= corr;
      float c4[4];
#pragma unroll
      for (int j = 0; j < 4; j++) c4[j] = __shfl(corr, lg * 4 + j);  // corr for q=4lg+j
#pragma unroll
      for (int nf = 0; nf < 16; nf++)
#pragma unroll
        for (int j = 0; j < 4; j++) o[nf][j] *= c4[j];
    }
    float rs = 0.f;
#pragma unroll
    for (int nf = 0; nf < 2; nf++) {
      us4 pk;
#pragma unroll
      for (int j = 0; j < 4; j++) {
        float p = __expf(s[nf][j] - m);
        rs += p;
        pk[j] = f2bf(p);
      }
      *reinterpret_cast<us4*>(&Pl[wave][lr][nf * 16 + lg * 4]) = pk;
    }
    rs += __shfl_xor(rs, 16);
    rs += __shfl_xor(rs, 32);
    lsum += rs;

    // ---- O += P * V : V from swizzled LDS ----
    __builtin_amdgcn_s_setprio(1);
    {
      bf16x8 pa = ldb8(&Pl[wave][lr][lg * 8]);
#pragma unroll
      for (int nf = 0; nf < 16; nf++) {
        int d = nf * 16 + lr;
        bf16x8 vb = ldb8(&Vl[cur][d * 32 + (((lg * 16) ^ (((d >> 1) & 3) << 4)) >> 1)]);
        o[nf] = mfma_bf16(pa, vb, o[nf]);
      }
    }
    __builtin_amdgcn_s_setprio(0);

    __syncthreads();   // drains stage loads; next iter flips buffers
  }

  // ---- write partials (unnormalized o in bf16; m/l in f32 at q = lr) ----
  const size_t rowbase = (size_t)h * (B_ * T_) + (size_t)b * T_;
#pragma unroll
  for (int nf = 0; nf < 16; nf++) {
#pragma unroll
    for (int j = 0; j < 4; j++) {
      int q = qt * 64 + wave * 16 + lg * 4 + j;
      op[(rowbase + q) * D_ + nf * 16 + lr] = f2bf(o[nf][j]);
    }
  }
  if (lg == 0) {
    int q = qt * 64 + wave * 16 + lr;
    ml[rowbase + q] = make_float2(m, lsum);
  }
}

// ---------------------------------------------------------------------------
// Kernel 4: merge NSPLIT partials.  grid (B*T/4), block 256: 4 rows/block.
// ---------------------------------------------------------------------------
__global__ __launch_bounds__(256) void merge_kernel(const unsigned short* __restrict__ op,
                                                    const float2* __restrict__ ml,
                                                    float* __restrict__ out) {
  const int tid = threadIdx.x;
  const int row = blockIdx.x * 4 + (tid >> 6);
  const int d0 = (tid & 63) * 4;

  float mh[NSPLIT], lh[NSPLIT];
  float M = -__builtin_inff();
#pragma unroll
  for (int hh = 0; hh < NSPLIT; hh++) {
    float2 v = ml[(size_t)hh * (B_ * T_) + row];
    mh[hh] = v.x; lh[hh] = v.y;
    M = fmaxf(M, v.x);
  }
  float e[NSPLIT], den = 0.f;
#pragma unroll
  for (int hh = 0; hh < NSPLIT; hh++) {
    e[hh] = __expf(mh[hh] - M);
    den += e[hh] * lh[hh];
  }
  const float inv = 1.0f / den;

  float acc[4] = {0.f, 0.f, 0.f, 0.f};
#pragma unroll
  for (int hh = 0; hh < NSPLIT; hh++) {
    us4 p = *reinterpret_cast<const us4*>(
        &op[((size_t)hh * (B_ * T_) + row) * D_ + d0]);
#pragma unroll
    for (int j = 0; j < 4; j++) acc[j] += e[hh] * bf2f(p[j]);
  }
  float4 r;
  r.x = acc[0] * inv; r.y = acc[1] * inv; r.z = acc[2] * inv; r.w = acc[3] * inv;
  *reinterpret_cast<float4*>(&out[(size_t)row * D_ + d0]) = r;
}

// ---------------------------------------------------------------------------
extern "C" void kernel_launch(void* const* d_in, const int* in_sizes, int n_in,
                              void* d_out, int out_size, void* d_ws, size_t ws_size,
                              hipStream_t stream) {
  const float* X  = (const float*)d_in[0];
  const float* Wq = (const float*)d_in[1];
  const float* Wk = (const float*)d_in[2];
  const float* Wv = (const float*)d_in[3];
  float* out = (float*)d_out;

  char* ws = (char*)d_ws;
  // Wt 0.75MB | Qs 8MB | Kb 8MB | Vt 8MB | op 16MB (aliased w/ Xb) | ml 0.25MB
  unsigned short* Wt = (unsigned short*)ws;
  unsigned short* Qs = (unsigned short*)(ws + 786432);
  unsigned short* Kb = (unsigned short*)(ws + 786432 + 8388608);
  unsigned short* Vt = (unsigned short*)(ws + 786432 + 2 * 8388608);
  unsigned short* op = (unsigned short*)(ws + 786432 + 3 * 8388608);
  unsigned short* Xb = op;   // alias: Xb consumed by proj before flash writes op
  float2* ml        = (float2*)(ws + 786432 + 3 * 8388608 + (size_t)NSPLIT * B_ * T_ * D_ * 2);

  xb_kernel<<<dim3((B_ * T_ * F_) / (256 * 8)), 256, 0, stream>>>(X, Xb);
  tw_kernel<<<dim3(F_ / 64, D_ / 64, 3), 256, 0, stream>>>(Wq, Wk, Wv, Wt);
  proj_kernel<<<dim3((B_ * T_) / 128, D_ / 128, 3), 256, 0, stream>>>(Xb, Wt, Qs, Kb, Vt);
  flash_kernel<<<dim3(B_, T_ / 64, NSPLIT), 256, 0, stream>>>(Qs, Kb, Vt, op, ml);
  merge_kernel<<<dim3(B_ * T_ / 4), 256, 0, stream>>>(op, ml, out);
}